// Round 8
// baseline (107.221 us; speedup 1.0000x reference)
//
#include <hip/hip_runtime.h>
#include <stdint.h>

typedef short bf16x8 __attribute__((ext_vector_type(8)));
typedef unsigned short u16x8 __attribute__((ext_vector_type(8)));
typedef float f32x4 __attribute__((ext_vector_type(4)));
typedef float f32x8 __attribute__((ext_vector_type(8)));

constexpr int BT_TOT = 768;   // B*T
constexpr int M_N    = 512;   // nodes (contraction length for stage 1)
constexpr int DD     = 64;    // Din = Dout
constexpr int WROW   = 72;    // W' row stride in route_mm (144B, bank step 4)

__device__ __forceinline__ unsigned short f2bf(float f) {
  unsigned u = __builtin_bit_cast(unsigned, f);
  u += 0x7fffu + ((u >> 16) & 1u);          // RNE
  return (unsigned short)(u >> 16);
}
__device__ __forceinline__ unsigned pk2(float a, float b) {
  return (unsigned)f2bf(a) | ((unsigned)f2bf(b) << 16);
}

// ---------------- prep: adj f32 -> bf16 (once) ----------------
__global__ __launch_bounds__(256)
void prep_adj(const float* __restrict__ adjg, unsigned short* __restrict__ wsadj) {
  int i = (blockIdx.x * 256 + threadIdx.x) * 8;
  f32x8 a = *(const f32x8*)(adjg + i);
  u16x8 r;
  #pragma unroll
  for (int j = 0; j < 8; ++j) r[j] = f2bf(a[j]);
  *(u16x8*)(wsadj + i) = r;
}

// ---------------- Kernel A v8 ----------------
// H[bt][m][d] = sum_n adj[m][n]*x[bt][n][d] (bf16 into low 128B of d_out rows).
// WG = 256 thr / 4 waves = 1 bt x 128 m. adj fragments come STRAIGHT FROM
// GLOBAL (bf16 ws copy; one 64B line per (m,k-slice), L2-resident) — no adj
// LDS traffic. x: coalesced f32 loads -> in-register butterfly transpose
// (verified v6/v7) -> swizzled xT (verified layout) -> b128 fragment reads.
// 8 chunks of 64 n, double-buffered, ONE barrier per chunk. 4 WG/CU so
// barrier waits of one WG overlap compute of the others.
template<bool WS>
__global__ __launch_bounds__(256, 4)
void gconv_h(const float* __restrict__ xg,             // [768][512][64] f32
             const float* __restrict__ adjf,           // [512][512] f32 (fallback)
             const unsigned short* __restrict__ adjb,  // [512][512] bf16 (ws path)
             char* __restrict__ hout)
{
  __shared__ __align__(16) char xlds[2][8192];   // xT dbuf: [64 d][64 n] bf16, swizzled

  const int wid  = blockIdx.x;          // 0..3071, bijective XCD swizzle (3072%8==0)
  const int xcd  = wid & 7;
  const int slot = wid >> 3;            // 0..383
  const int mb   = slot & 3;            // 4 consecutive slots share bt -> x L2-amortized
  const int bt   = (slot >> 2) * 8 + xcd;

  const int tid  = threadIdx.x;
  const int lane = tid & 63;
  const int wv   = tid >> 6;            // wave 0..3: owns m in [wv*32, wv*32+32)
  const int l15  = lane & 15;
  const int gg   = lane >> 4;           // k-group / butterfly row
  const int c4   = l15;                 // d-quad for staging

  const float* xsrc = xg + (size_t)bt * (M_N * DD);

  f32x4 xv[4];
  auto load_x = [&](int c) {            // coalesced: wave reads 4 n x 64 d = 1KB contig
    #pragma unroll
    for (int s = 0; s < 4; ++s) {
      const int n4 = s*4 + wv;
      xv[s] = *(const f32x4*)(xsrc + (size_t)(c*64 + n4*4 + gg) * DD + c4*4);
    }
  };
  auto write_x = [&](int c) {           // verified butterfly: lane ends with d=c4*4+gg
    char* xt = &xlds[c & 1][0];
    const int d = c4*4 + gg;
    #pragma unroll
    for (int s = 0; s < 4; ++s) {
      const int n4 = s*4 + wv;
      unsigned u0 = pk2(xv[s].x, xv[s].y);
      unsigned u1 = pk2(xv[s].z, xv[s].w);
      unsigned t0 = __shfl_xor(u0, 32);
      unsigned t1 = __shfl_xor(u1, 32);
      unsigned v0 = (gg & 2) ? t1 : u0;
      unsigned v1 = (gg & 2) ? u1 : t0;
      unsigned s0 = __shfl_xor(v0, 16);
      unsigned s1 = __shfl_xor(v1, 16);
      unsigned F0 = (gg & 1) ? ((s0 >> 16) | (v0 & 0xFFFF0000u))
                             : ((v0 & 0xFFFFu) | (s0 << 16));
      unsigned F1 = (gg & 1) ? ((s1 >> 16) | (v1 & 0xFFFF0000u))
                             : ((v1 & 0xFFFFu) | (s1 << 16));
      uint2 o2; o2.x = F0; o2.y = F1;
      *(uint2*)(xt + d*128 + (((n4 >> 1) ^ (d & 7)) * 16) + (n4 & 1)*8) = o2;
    }
  };

  f32x4 acc[2][4];
  #pragma unroll
  for (int mt = 0; mt < 2; ++mt)
    #pragma unroll
    for (int dt = 0; dt < 4; ++dt) acc[mt][dt] = f32x4{0.f,0.f,0.f,0.f};

  load_x(0);
  write_x(0);
  __syncthreads();

  #pragma unroll
  for (int c = 0; c < 8; ++c) {
    // adj fragments for chunk c: issue FIRST so the x-prefetch (issued after)
    // can stay outstanding past the afr vmcnt-waits (vmcnt retires FIFO).
    u16x8 afr[2][2];                    // [kl][mt]
    if (WS) {
      #pragma unroll
      for (int kl = 0; kl < 2; ++kl)
        #pragma unroll
        for (int mt = 0; mt < 2; ++mt) {
          const int m = mb*128 + wv*32 + mt*16 + l15;
          afr[kl][mt] = *(const u16x8*)(adjb + (size_t)m*M_N + c*64 + kl*32 + gg*8);
        }
    } else {
      #pragma unroll
      for (int kl = 0; kl < 2; ++kl)
        #pragma unroll
        for (int mt = 0; mt < 2; ++mt) {
          const int m = mb*128 + wv*32 + mt*16 + l15;
          f32x8 a = *(const f32x8*)(adjf + (size_t)m*M_N + c*64 + kl*32 + gg*8);
          u16x8 r;
          #pragma unroll
          for (int j = 0; j < 8; ++j) r[j] = f2bf(a[j]);
          afr[kl][mt] = r;
        }
    }

    if (c < 7) load_x(c + 1);           // x prefetch: hides under MFMA phase

    const char* xt = &xlds[c & 1][0];
    #pragma unroll
    for (int kl = 0; kl < 2; ++kl) {
      bf16x8 bfx[4];
      #pragma unroll
      for (int dt = 0; dt < 4; ++dt)
        bfx[dt] = __builtin_bit_cast(bf16x8,
            *(const u16x8*)(xt + (dt*16 + l15)*128 + ((kl*4 + gg) ^ (l15 & 7))*16));
      #pragma unroll
      for (int mt = 0; mt < 2; ++mt)
        #pragma unroll
        for (int dt = 0; dt < 4; ++dt)
          acc[mt][dt] = __builtin_amdgcn_mfma_f32_16x16x32_bf16(
              __builtin_bit_cast(bf16x8, afr[kl][mt]), bfx[dt], acc[mt][dt], 0,0,0);
    }

    if (c < 7) { write_x(c + 1); __syncthreads(); }
  }

  // epilogue: H store (bf16, low half of each d_out row) — verified pattern
  #pragma unroll
  for (int mt = 0; mt < 2; ++mt)
    #pragma unroll
    for (int dt = 0; dt < 4; ++dt)
      #pragma unroll
      for (int r = 0; r < 4; ++r) {
        int m = mb*128 + wv*32 + mt*16 + gg*4 + r;   // C row = (lane>>4)*4 + reg
        int d = dt*16 + l15;
        *(unsigned short*)(hout + ((size_t)bt*M_N + m)*256 + 2*d)
            = f2bf(acc[mt][dt][r]);
      }
}

// ---------------- Kernel B (unchanged, verified) ----------------
__global__ __launch_bounds__(256, 4)
void route_mm(const char* __restrict__ hin,
              const float* __restrict__ wgt,
              const float* __restrict__ bias,
              float* __restrict__ outg)
{
  __shared__ unsigned short wb[128 * WROW];

  const int m0    = blockIdx.x * 2;
  const int btblk = blockIdx.y * 64;
  const int tid   = threadIdx.x;
  const int lane  = tid & 63;
  const int wv    = tid >> 6;
  const int l15   = lane & 15;
  const int gg    = lane >> 4;
  const int dp    = tid & 31;
  const int lo    = tid >> 5;

  { const float* q = wgt + ((size_t)m0*64 + dp*2)*64 + lo*8;
    f32x8 w0 = *(const f32x8*)q;          f32x8 w1 = *(const f32x8*)(q+64);
    f32x8 w2 = *(const f32x8*)(q+4096);   f32x8 w3 = *(const f32x8*)(q+4160);
    #pragma unroll
    for (int e = 0; e < 8; ++e) {
      int lrow = lo*8 + e;
      unsigned v0 = pk2(w0[e], w1[e]);
      unsigned v1 = pk2(w2[e], w3[e]);
      *(unsigned*)(wb + lrow*WROW + dp*2)        = v0;
      *(unsigned*)(wb + (64 + lrow)*WROW + dp*2) = v1;
    }
  }
  __syncthreads();

  const int btw0 = btblk + wv*16;

  #pragma unroll
  for (int mm = 0; mm < 2; ++mm) {
    const int m = m0 + mm;
    bf16x8 afr[2];
    #pragma unroll
    for (int ks = 0; ks < 2; ++ks) {
      const char* hp = hin + ((size_t)(btw0 + l15)*M_N + m)*256 + ks*64 + gg*16;
      afr[ks] = __builtin_bit_cast(bf16x8, *(const u16x8*)hp);
    }
    f32x4 acc[4];
    #pragma unroll
    for (int lt = 0; lt < 4; ++lt) acc[lt] = f32x4{0.f,0.f,0.f,0.f};
    #pragma unroll
    for (int lt = 0; lt < 4; ++lt)
      #pragma unroll
      for (int ks = 0; ks < 2; ++ks) {
        bf16x8 bfr = __builtin_bit_cast(bf16x8,
            *(const u16x8*)(wb + (mm*64 + lt*16 + l15)*WROW + ks*32 + gg*8));
        acc[lt] = __builtin_amdgcn_mfma_f32_16x16x32_bf16(afr[ks], bfr, acc[lt], 0,0,0);
      }
    #pragma unroll
    for (int lt = 0; lt < 4; ++lt) {
      float bv = bias[m*64 + lt*16 + l15];
      #pragma unroll
      for (int r = 0; r < 4; ++r) {
        size_t row = (size_t)(btw0 + gg*4 + r)*M_N + m;
        outg[row*64 + lt*16 + l15] = acc[lt][r] + bv;
      }
    }
  }
}

extern "C" void kernel_launch(void* const* d_in, const int* in_sizes, int n_in,
                              void* d_out, int out_size, void* d_ws, size_t ws_size,
                              hipStream_t stream) {
  const float* xg   = (const float*)d_in[0];
  const float* adjg = (const float*)d_in[1];
  const float* wgt  = (const float*)d_in[2];
  const float* bg   = (const float*)d_in[3];

  const size_t adj_bf_bytes = (size_t)M_N * M_N * 2;   // 512 KB
  if (ws_size >= adj_bf_bytes) {
    unsigned short* wsadj = (unsigned short*)d_ws;
    prep_adj<<<dim3(M_N * M_N / (256 * 8)), dim3(256), 0, stream>>>(adjg, wsadj);
    gconv_h<true><<<dim3(3072), dim3(256), 0, stream>>>(
        xg, adjg, wsadj, (char*)d_out);
  } else {
    gconv_h<false><<<dim3(3072), dim3(256), 0, stream>>>(
        xg, adjg, nullptr, (char*)d_out);
  }
  route_mm<<<dim3(M_N/2, BT_TOT/64), dim3(256), 0, stream>>>(
      (const char*)d_out, wgt, bg, (float*)d_out);
}